// Round 12
// baseline (355.911 us; speedup 1.0000x reference)
//
#include <hip/hip_runtime.h>

// Fused RMSNorm(Q,K) + NeoX RoPE + V passthrough for packed QKV. All f32.
// Block = 256 thr, 4 tokens. LDS trig table (exact reference f32 phase chain).
// Latency-optimized main loop:
//   - all 6 float4 loads per token issued up front (1 HBM round-trip/token)
//   - 16-lane RMS reduction via DPP adds (quad_perm xor1/xor2, row_half_mirror,
//     row_mirror) = pure VALU, no ds_swizzle latency
//   - the 3 head-blocks' reduction chains interleaved so they pipeline
// NT stores kept from round 10 (touch-once output; preserves L3 for input).

namespace {

constexpr int kNumQ = 32;
constexpr int kNumK = 8;
constexpr int kHead = 128;
constexpr int kRow  = (kNumQ + 2 * kNumK) * kHead;  // 6144
constexpr int kHalf = 64;                            // rotary_dim/2
constexpr int kTPB  = 4;                             // tokens per block

typedef float f32x4 __attribute__((ext_vector_type(4)));

__device__ __forceinline__ void nt_store4(float* p, float x, float y, float z,
                                          float w) {
  f32x4 v;
  v.x = x; v.y = y; v.z = z; v.w = w;
  __builtin_nontemporal_store(v, reinterpret_cast<f32x4*>(p));
}

// v + (v from lane permuted by DPP ctrl), within 16-lane rows. VALU-only.
// DPP control must be an immediate -> template parameter.
template <int kCtrl>
__device__ __forceinline__ float dpp_add(float v) {
  int i = __float_as_int(v);
  int j = __builtin_amdgcn_update_dpp(i, i, kCtrl, 0xf, 0xf, false);
  return v + __int_as_float(j);
}

// Full 16-lane sum via 4 DPP steps: quad_perm xor1 (0xB1), quad_perm xor2
// (0x4E), row_half_mirror (0x141), row_mirror (0x140). Three chains
// interleaved so the 3 reductions pipeline.
__device__ __forceinline__ void dpp_reduce3(float& s0, float& s1, float& s2) {
  s0 = dpp_add<0xB1>(s0);
  s1 = dpp_add<0xB1>(s1);
  s2 = dpp_add<0xB1>(s2);
  s0 = dpp_add<0x4E>(s0);
  s1 = dpp_add<0x4E>(s1);
  s2 = dpp_add<0x4E>(s2);
  s0 = dpp_add<0x141>(s0);
  s1 = dpp_add<0x141>(s1);
  s2 = dpp_add<0x141>(s2);
  s0 = dpp_add<0x140>(s0);
  s1 = dpp_add<0x140>(s1);
  s2 = dpp_add<0x140>(s2);
}

__device__ __forceinline__ float dot8(const float4& a, const float4& b) {
  return a.x * a.x + a.y * a.y + a.z * a.z + a.w * a.w +
         b.x * b.x + b.y * b.y + b.z * b.z + b.w * b.w;
}

__device__ __forceinline__ void rope_store(float* op, const float4& a,
                                           const float4& b, const float4& w1,
                                           const float4& w2, float inv,
                                           const float4& cz, const float4& sz) {
  const float y1x = a.x * inv * w1.x, y1y = a.y * inv * w1.y;
  const float y1z = a.z * inv * w1.z, y1w = a.w * inv * w1.w;
  const float y2x = b.x * inv * w2.x, y2y = b.y * inv * w2.y;
  const float y2z = b.z * inv * w2.z, y2w = b.w * inv * w2.w;
  nt_store4(op, y1x * cz.x - y2x * sz.x, y1y * cz.y - y2y * sz.y,
            y1z * cz.z - y2z * sz.z, y1w * cz.w - y2w * sz.w);
  nt_store4(op + kHalf, y2x * cz.x + y1x * sz.x, y2y * cz.y + y1y * sz.y,
            y2z * cz.z + y1z * sz.z, y2w * cz.w + y1w * sz.w);
}

__global__ __launch_bounds__(256) void rope_qknorm_kernel(
    const float* __restrict__ qkv,
    const float* __restrict__ qw,
    const float* __restrict__ kw,
    const int* __restrict__ positions,
    float* __restrict__ out,
    int tokens) {
  const int tid = threadIdx.x;
  const int t0  = blockIdx.x * kTPB;

  __shared__ float s_cos[kTPB][kHalf];
  __shared__ float s_sin[kTPB][kHalf];

  {
    // One phase per thread: tl = tid>>6 (token in block), i = tid&63 (freq).
    const int tl = tid >> 6;
    const int i  = tid & 63;
    const int t  = t0 + tl;
    if (t < tokens) {
      // Reference chain: inv_freq = f32(1/10000^(i/64)); phase = f32(pos*inv_freq);
      // accurate sin/cos via exact rint + f64-mulsub range reduction.
      const double log2b = 13.287712379549449629;  // log2(10000)
      const float p = (float)exp2((double)i * (log2b / 64.0));
      const float inv_freq = 1.0f / p;
      const float phase = (float)positions[t] * inv_freq;  // f32 round = ref
      const float k = rintf(phase * 0.15915494309189535f); // 1/(2pi)
      const double r = (double)phase - (double)k * 6.283185307179586476925287;
      const float pr = (float)r;                           // |pr| <= pi + eps
      s_cos[tl][i] = cosf(pr);
      s_sin[tl][i] = sinf(pr);
    }
  }
  __syncthreads();

  const int g = tid >> 4;   // head-group id in block (0..15)
  const int l = tid & 15;   // lane in group; owns rope-pair elems [l*4, l*4+4)
  const bool thirdIsK = (g < kNumK);  // head 32+g: K for g<8, else V

  const float4 qw1 = *reinterpret_cast<const float4*>(qw + l * 4);
  const float4 qw2 = *reinterpret_cast<const float4*>(qw + kHalf + l * 4);
  const float4 kw1 = *reinterpret_cast<const float4*>(kw + l * 4);
  const float4 kw2 = *reinterpret_cast<const float4*>(kw + kHalf + l * 4);

  const int base = g * kHead + l * 4;  // head g, first rope half

  #pragma unroll
  for (int tl = 0; tl < kTPB; ++tl) {
    const int t = t0 + tl;
    if (t >= tokens) break;
    const float* row  = qkv + (size_t)t * kRow + base;
    float*       orow = out + (size_t)t * kRow + base;

    // All six independent 16B loads issued up front.
    const float4 a0 = *reinterpret_cast<const float4*>(row);
    const float4 b0 = *reinterpret_cast<const float4*>(row + kHalf);
    const float4 a1 = *reinterpret_cast<const float4*>(row + 16 * kHead);
    const float4 b1 = *reinterpret_cast<const float4*>(row + 16 * kHead + kHalf);
    const float4 a2 = *reinterpret_cast<const float4*>(row + 32 * kHead);
    const float4 b2 = *reinterpret_cast<const float4*>(row + 32 * kHead + kHalf);

    const float4 cz = *reinterpret_cast<const float4*>(&s_cos[tl][l * 4]);
    const float4 sz = *reinterpret_cast<const float4*>(&s_sin[tl][l * 4]);

    float ss0 = dot8(a0, b0);
    float ss1 = dot8(a1, b1);
    float ss2 = dot8(a2, b2);   // garbage for V waves; never used there
    dpp_reduce3(ss0, ss1, ss2);

    const float inv0 = rsqrtf(ss0 * (1.0f / 128.0f) + 1e-6f);
    const float inv1 = rsqrtf(ss1 * (1.0f / 128.0f) + 1e-6f);
    const float inv2 = rsqrtf(ss2 * (1.0f / 128.0f) + 1e-6f);

    rope_store(orow, a0, b0, qw1, qw2, inv0, cz, sz);                // Q head g
    rope_store(orow + 16 * kHead, a1, b1, qw1, qw2, inv1, cz, sz);   // Q head 16+g
    if (thirdIsK) {                                                  // wave-uniform
      rope_store(orow + 32 * kHead, a2, b2, kw1, kw2, inv2, cz, sz); // K head
    } else {
      nt_store4(orow + 32 * kHead, a2.x, a2.y, a2.z, a2.w);          // V: raw copy
      nt_store4(orow + 32 * kHead + kHalf, b2.x, b2.y, b2.z, b2.w);
    }
  }
}

}  // namespace

extern "C" void kernel_launch(void* const* d_in, const int* in_sizes, int n_in,
                              void* d_out, int out_size, void* d_ws, size_t ws_size,
                              hipStream_t stream) {
  const float* qkv     = (const float*)d_in[0];
  const float* qw      = (const float*)d_in[1];
  const float* kw      = (const float*)d_in[2];
  const int* positions = (const int*)d_in[3];
  float* out           = (float*)d_out;

  const int tokens = in_sizes[3];  // positions element count == NUM_TOKENS
  const int blocks = (tokens + kTPB - 1) / kTPB;  // 2048 @ 8192 tokens
  rope_qknorm_kernel<<<blocks, 256, 0, stream>>>(qkv, qw, kw, positions, out,
                                                 tokens);
}